// Round 7
// baseline (187.623 us; speedup 1.0000x reference)
//
#include <hip/hip_runtime.h>
#include <hip/hip_bf16.h>

// Problem constants (B,T,C,H) = (8,1024,768,12), D=64
#define Bb 8
#define Tt 1024
#define Cc 768
#define Hh 12
#define Dd 64
#define M_ROWS (Bb * Tt)      // 8192
#define QKV_N (3 * Cc)        // 2304

typedef __attribute__((ext_vector_type(8))) short s16x8;   // 8 x bf16
typedef __attribute__((ext_vector_type(4))) short s16x4;   // 4 x bf16
typedef __attribute__((ext_vector_type(4))) float f32x4;

#define AS1 __attribute__((address_space(1)))
#define AS3 __attribute__((address_space(3)))

static __device__ __forceinline__ short f2bf(float f) {
    union { float f; unsigned u; } v; v.f = f;
    unsigned r = (v.u + 0x7fffu + ((v.u >> 16) & 1u)) >> 16;  // RNE
    return (short)r;
}
// two f32 -> packed bf16x2 (TRUNCATION) in one v_perm_b32
static __device__ __forceinline__ unsigned pkt(float hi, float lo) {
    union { float f; unsigned u; } a, b; a.f = hi; b.f = lo;
    return __builtin_amdgcn_perm(a.u, b.u, 0x07060302u);
}

// ---------------------------------------------------------------------------
// Prep: fp32->bf16 casts + RoPE cos/sin table, one launch.
// wqkv rows are PERMUTED for q/k sections (sigma = row^0x30 for within-head
// quadrants 1,2): RoPE partners (i,i+32) become ADJACENT 16-col tiles in the
// qkv output, so any 32-col-aligned wave tile holds complete rotation pairs.
// Q.K is invariant (same sigma on q and k); v rows untouched.
// ---------------------------------------------------------------------------
static __device__ __forceinline__ void cast8(const float* __restrict__ in,
                                             short* __restrict__ out, int i) {
    const float4 a = ((const float4*)in)[i * 2];
    const float4 b = ((const float4*)in)[i * 2 + 1];
    s16x8 f;
    f[0] = f2bf(a.x); f[1] = f2bf(a.y); f[2] = f2bf(a.z); f[3] = f2bf(a.w);
    f[4] = f2bf(b.x); f[5] = f2bf(b.y); f[6] = f2bf(b.z); f[7] = f2bf(b.w);
    ((s16x8*)out)[i] = f;
}

#define S1 (M_ROWS * Cc / 8)   // 786432
#define S2 (QKV_N * Cc / 8)    // 221184
#define S3 (Cc * Cc / 8)       // 73728
#define SROPE (Tt * 32)        // 32768
#define PREP_THREADS (S1 + S2 + S3 + SROPE)  // 1114112 = 4352 * 256

__global__ __launch_bounds__(256) void prep_kernel(const float* __restrict__ x,
                                                   const float* __restrict__ wqkv,
                                                   const float* __restrict__ wproj,
                                                   short* __restrict__ xb,
                                                   short* __restrict__ wqkvb,
                                                   short* __restrict__ wprojb,
                                                   float2* __restrict__ cs) {
    int idx = blockIdx.x * blockDim.x + threadIdx.x;
    if (idx < S1) { cast8(x, xb, idx); return; }
    idx -= S1;
    if (idx < S2) {
        // permuted cast for wqkv: position-row n holds original row tau(n)
        int row = idx / 96;          // 768/8 = 96 chunks per row
        int c8  = idx - row * 96;
        int q2 = (row >> 4) & 3;
        int src = (row < 2 * Cc && (q2 == 1 || q2 == 2)) ? (row ^ 0x30) : row;
        const float4 a = ((const float4*)(wqkv + (size_t)src * Cc))[c8 * 2];
        const float4 b = ((const float4*)(wqkv + (size_t)src * Cc))[c8 * 2 + 1];
        s16x8 f;
        f[0] = f2bf(a.x); f[1] = f2bf(a.y); f[2] = f2bf(a.z); f[3] = f2bf(a.w);
        f[4] = f2bf(b.x); f[5] = f2bf(b.y); f[6] = f2bf(b.z); f[7] = f2bf(b.w);
        ((s16x8*)wqkvb)[idx] = f;
        return;
    }
    idx -= S2;
    if (idx < S3) { cast8(wproj, wprojb, idx); return; }
    idx -= S3;
    {
        int t = idx >> 5, i = idx & 31;
        float inv_freq = exp2f(-0.41524101186092037f * (float)i);  // log2(1e4)/32
        float fr = (float)t * inv_freq;
        float2 v; v.x = cosf(fr); v.y = sinf(fr);
        cs[idx] = v;
    }
}

// ---------------------------------------------------------------------------
// bf16 MFMA GEMM (NT): out[m][n] = sum_k A[m][k] * B[n][k]
// 128 x TN tile, BK=32, waves in 2x2 grid: each wave 64 rows x TN/2 cols.
// qkv TN=192 -> 768 blocks = 3/CU. Double-buffered global_load_lds pipeline
// (1 barrier/iter) + source-side XOR swizzle -> conflict-free ds_read_b128.
// XCD bm-stripe swizzle. MODE 1: bf16 out + fused RoPE epilogue.
// R7: q-scale now folds log2(e) (0.125*1.4426950408889634) so attn can use
// exp2f directly (saves one v_mul per exp in the attn inner loop).
// NOTE (R1-R5 post-mortem): ALL deep-pipeline variants lost. GEMM
// pipelining on this kernel is permanently abandoned.
// ---------------------------------------------------------------------------
template <int MODE, int TN>
__global__ __launch_bounds__(256, 3) void gemm_nt_mfma(const short* __restrict__ A,
                                                       const short* __restrict__ B,
                                                       void* __restrict__ Cout,
                                                       const float2* __restrict__ cs,
                                                       int M, int N, int K, int nblocks) {
    __shared__ short As[2][128 * 32];
    __shared__ short Bs[2][TN * 32];
    constexpr int NTW = TN / 32;   // col-tiles per wave

    const int wave = threadIdx.x >> 6;
    const int lane = threadIdx.x & 63;
    const int l16  = lane & 15;
    const int quad = lane >> 4;
    const int wr = wave >> 1;      // 0,1 row half
    const int wc = wave & 1;       // 0,1 col half

    // XCD-aware swizzle (M/128 divisible by 8)
    const int mb8  = (M >> 7) >> 3;
    const int xcd  = blockIdx.x & 7;
    const int slot = blockIdx.x >> 3;
    const int bm = (xcd * mb8 + slot / nblocks) * 128;
    const int bn = (slot % nblocks) * TN;

    f32x4 acc[4][NTW] = {};

    auto stage = [&](int k0, int buf) {
#pragma unroll
        for (int j = 0; j < 2; j++) {                 // A: 512 chunks
            const int D = j * 256 + wave * 64 + lane;
            const int G = D >> 3;
            const int s = (G << 3) | ((D & 7) ^ (G & 7));
            const int m = s >> 2, c4 = (s & 3) * 8;
            __builtin_amdgcn_global_load_lds(
                (const AS1 unsigned*)(A + (size_t)(bm + m) * K + k0 + c4),
                (AS3 unsigned*)&As[buf][(j * 256 + wave * 64) * 8], 16, 0, 0);
        }
        constexpr int BCH = TN * 4;                   // B chunks
#pragma unroll
        for (int j = 0; j < (BCH + 255) / 256; j++) {
            if (BCH % 256 == 0 || j * 256 + wave * 64 < BCH) {  // wave-uniform
                const int D = j * 256 + wave * 64 + lane;
                const int G = D >> 3;
                const int s = (G << 3) | ((D & 7) ^ (G & 7));
                const int m = s >> 2, c4 = (s & 3) * 8;
                __builtin_amdgcn_global_load_lds(
                    (const AS1 unsigned*)(B + (size_t)(bn + m) * K + k0 + c4),
                    (AS3 unsigned*)&Bs[buf][(j * 256 + wave * 64) * 8], 16, 0, 0);
            }
        }
    };

    const int nIter = K >> 5;   // K/32
    stage(0, 0);
    for (int kt = 0; kt < nIter; kt++) {
        const int buf = kt & 1;
        __syncthreads();                       // drains loads for tile kt
        if (kt + 1 < nIter) stage((kt + 1) << 5, buf ^ 1);

        s16x8 af[4];
#pragma unroll
        for (int mt = 0; mt < 4; mt++) {
            const int m = wr * 64 + mt * 16 + l16;
            const int d = ((m & 1) * 4 + quad) ^ ((m >> 1) & 7);
            af[mt] = *(const s16x8*)&As[buf][(m >> 1) * 64 + d * 8];
        }
#pragma unroll
        for (int nt = 0; nt < NTW; nt++) {
            const int n = wc * (TN / 2) + nt * 16 + l16;
            const int d = ((n & 1) * 4 + quad) ^ ((n >> 1) & 7);
            s16x8 bf = *(const s16x8*)&Bs[buf][(n >> 1) * 64 + d * 8];
#pragma unroll
            for (int mt = 0; mt < 4; mt++)
                acc[mt][nt] = __builtin_amdgcn_mfma_f32_16x16x32_bf16(
                    af[mt], bf, acc[mt][nt], 0, 0, 0);
        }
    }

    if constexpr (MODE == 0) {
#pragma unroll
        for (int mt = 0; mt < 4; mt++)
#pragma unroll
            for (int r = 0; r < 4; r++) {
                const size_t row = bm + wr * 64 + mt * 16 + quad * 4 + r;
#pragma unroll
                for (int nt = 0; nt < NTW; nt++)
                    ((float*)Cout)[row * N + bn + wc * (TN / 2) + nt * 16 + l16] =
                        acc[mt][nt][r];
            }
    } else {
        const bool is_v = (bn >= 2 * Cc);
        if (is_v) {
#pragma unroll
            for (int mt = 0; mt < 4; mt++)
#pragma unroll
                for (int r = 0; r < 4; r++) {
                    const size_t row = bm + wr * 64 + mt * 16 + quad * 4 + r;
#pragma unroll
                    for (int nt = 0; nt < NTW; nt++)
                        ((short*)Cout)[row * N + bn + wc * (TN / 2) + nt * 16 + l16] =
                            f2bf(acc[mt][nt][r]);
                }
        } else {
            // q gets 1/sqrt(D) * log2(e) = 0.125 * 1.4426950408889634
            const float scale = (bn < Cc) ? 0.18033688511112043f : 1.0f;
#pragma unroll
            for (int mt = 0; mt < 4; mt++) {
#pragma unroll
                for (int r = 0; r < 4; r++) {
                    const int row = bm + wr * 64 + mt * 16 + quad * 4 + r;
                    const int t = row & (Tt - 1);
                    short* cp = (short*)Cout + (size_t)row * N + bn + wc * (TN / 2);
#pragma unroll
                    for (int p = 0; p < NTW; p += 2) {   // adjacent-tile pairs
                        const int g = wc * NTW + p;       // global col-tile (even)
                        const int i0 = ((g & 2) ? 16 : 0) + l16;
                        const float2 c0 = cs[t * 32 + i0];
                        const float x1 = acc[mt][p][r];
                        const float x2 = acc[mt][p + 1][r];
                        cp[p * 16 + l16]        = f2bf((x1 * c0.x + x2 * c0.y) * scale);
                        cp[(p + 1) * 16 + l16]  = f2bf((-x1 * c0.y + x2 * c0.x) * scale);
                    }
                }
            }
        }
    }
}

// ---------------------------------------------------------------------------
// PROJ GEMM, double-pumped K-loop (R6, kept: neutral-to-slightly-positive):
//   stage TWO BK=32 tiles per round (4 bufs, 56 KB, 2 blocks/CU), ONE
//   __syncthreads per 2 tiles -> 12 rounds. MODE 0 epilogue (fp32 out).
// ---------------------------------------------------------------------------
template <int TN>
__global__ __launch_bounds__(256, 2) void gemm_nt_proj2(const short* __restrict__ A,
                                                        const short* __restrict__ B,
                                                        float* __restrict__ Cout,
                                                        int M, int N, int K, int nblocks) {
    __shared__ short As[2][2][128 * 32];   // [pair][tile]
    __shared__ short Bs[2][2][TN * 32];
    constexpr int NTW = TN / 32;   // col-tiles per wave

    const int wave = threadIdx.x >> 6;
    const int lane = threadIdx.x & 63;
    const int l16  = lane & 15;
    const int quad = lane >> 4;
    const int wr = wave >> 1;      // 0,1 row half
    const int wc = wave & 1;       // 0,1 col half

    // XCD-aware swizzle (M/128 divisible by 8)
    const int mb8  = (M >> 7) >> 3;
    const int xcd  = blockIdx.x & 7;
    const int slot = blockIdx.x >> 3;
    const int bm = (xcd * mb8 + slot / nblocks) * 128;
    const int bn = (slot % nblocks) * TN;

    f32x4 acc[4][NTW] = {};

    auto stage = [&](int k0, int p, int t) {
#pragma unroll
        for (int j = 0; j < 2; j++) {                 // A: 512 chunks
            const int D = j * 256 + wave * 64 + lane;
            const int G = D >> 3;
            const int s = (G << 3) | ((D & 7) ^ (G & 7));
            const int m = s >> 2, c4 = (s & 3) * 8;
            __builtin_amdgcn_global_load_lds(
                (const AS1 unsigned*)(A + (size_t)(bm + m) * K + k0 + c4),
                (AS3 unsigned*)&As[p][t][(j * 256 + wave * 64) * 8], 16, 0, 0);
        }
        constexpr int BCH = TN * 4;                   // B chunks
#pragma unroll
        for (int j = 0; j < (BCH + 255) / 256; j++) {
            if (BCH % 256 == 0 || j * 256 + wave * 64 < BCH) {  // wave-uniform
                const int D = j * 256 + wave * 64 + lane;
                const int G = D >> 3;
                const int s = (G << 3) | ((D & 7) ^ (G & 7));
                const int m = s >> 2, c4 = (s & 3) * 8;
                __builtin_amdgcn_global_load_lds(
                    (const AS1 unsigned*)(B + (size_t)(bn + m) * K + k0 + c4),
                    (AS3 unsigned*)&Bs[p][t][(j * 256 + wave * 64) * 8], 16, 0, 0);
            }
        }
    };

    const int nPair = K >> 6;   // K/64 double-rounds (768 -> 12)
    stage(0, 0, 0);
    stage(32, 0, 1);
    for (int it = 0; it < nPair; it++) {
        const int p = it & 1;
        __syncthreads();                       // drains both tiles of pair it
        if (it + 1 < nPair) {
            stage((2 * it + 2) << 5, p ^ 1, 0);
            stage((2 * it + 3) << 5, p ^ 1, 1);
        }
#pragma unroll
        for (int t = 0; t < 2; t++) {
            s16x8 af[4];
#pragma unroll
            for (int mt = 0; mt < 4; mt++) {
                const int m = wr * 64 + mt * 16 + l16;
                const int d = ((m & 1) * 4 + quad) ^ ((m >> 1) & 7);
                af[mt] = *(const s16x8*)&As[p][t][(m >> 1) * 64 + d * 8];
            }
#pragma unroll
            for (int nt = 0; nt < NTW; nt++) {
                const int n = wc * (TN / 2) + nt * 16 + l16;
                const int d = ((n & 1) * 4 + quad) ^ ((n >> 1) & 7);
                s16x8 bf = *(const s16x8*)&Bs[p][t][(n >> 1) * 64 + d * 8];
#pragma unroll
                for (int mt = 0; mt < 4; mt++)
                    acc[mt][nt] = __builtin_amdgcn_mfma_f32_16x16x32_bf16(
                        af[mt], bf, acc[mt][nt], 0, 0, 0);
            }
        }
    }

#pragma unroll
    for (int mt = 0; mt < 4; mt++)
#pragma unroll
        for (int r = 0; r < 4; r++) {
            const size_t row = bm + wr * 64 + mt * 16 + quad * 4 + r;
#pragma unroll
            for (int nt = 0; nt < NTW; nt++)
                Cout[row * N + bn + wc * (TN / 2) + nt * 16 + l16] = acc[mt][nt][r];
        }
}

// ---------------------------------------------------------------------------
// Flash attention v4 (R7): q-widened 2-wave blocks.
//   R6 analysis: attn is LDS-pipe-bound (~290 cyc LDS issue vs ~160 MFMA per
//   wave-round). Fix: 128-thread blocks, each wave owns 32 q-rows of BOTH
//   qa and qb (4 q-frags/wave) -> K/V fragment reads shared across 4 frags:
//   0.375 ds_read_b128 per MFMA vs 0.625 before (-40% LDS traffic/work).
//   Grid stays 768 balanced pair-blocks; LDS unchanged 36 KB (up to 4
//   blocks/CU). Wave-row ownership preserved: wave w owns rows [32w,32w+32)
//   in store_tile AND in the P-scratch aliasing (qb P in Ks[buf^1], qa P in
//   Vs[buf^1]).
//   + exp2f with log2e pre-folded into q-scale (qkv epilogue).
//   T5 setprio around MFMA clusters kept (R4 banked win).
// ---------------------------------------------------------------------------
#define KSP 72
#define VSP 72

__global__ __launch_bounds__(128, 2) void flash_attn(const short* __restrict__ qkv,
                                                     short* __restrict__ y) {
    __shared__ short Ks[2][64 * KSP];
    __shared__ short Vs[2][64 * VSP];

    const int wave = threadIdx.x >> 6;   // 0,1
    const int lane = threadIdx.x & 63;
    const int l16  = lane & 15;
    const int quad = lane >> 4;

    const int pair = blockIdx.x / 96;     // 0..7
    const int bh   = blockIdx.x % 96;
    const int h = bh % Hh;
    const int b = bh / Hh;
    const int qa_blk = pair;
    const int qb_blk = 15 - pair;
    const int q0a = qa_blk * 64 + wave * 32;   // this wave's 32-row band
    const int q0b = qb_blk * 64 + wave * 32;

    s16x8 qfa[2][2], qfb[2][2];
#pragma unroll
    for (int f = 0; f < 2; f++) {
        const short* qpa = qkv + (size_t)(b * Tt + q0a + f * 16 + l16) * QKV_N + h * Dd + quad * 8;
        const short* qpb = qkv + (size_t)(b * Tt + q0b + f * 16 + l16) * QKV_N + h * Dd + quad * 8;
        qfa[f][0] = *(const s16x8*)qpa;  qfa[f][1] = *(const s16x8*)(qpa + 32);
        qfb[f][0] = *(const s16x8*)qpb;  qfb[f][1] = *(const s16x8*)(qpb + 32);
    }

    f32x4 oa[2][4] = {}, ob[2][4] = {};
    float la[2] = {0.f, 0.f}, lb[2] = {0.f, 0.f};

    // K staging: 2 threads/row, 32 shorts each
    const int krow = threadIdx.x >> 1;          // 0..63
    const int kd0  = (threadIdx.x & 1) * 32;    // 0 or 32
    // V staging: 2 keys x 16 d per thread
    const int key2 = (threadIdx.x & 31) * 2;    // 0..62 step 2
    const int dv0  = (threadIdx.x >> 5) * 16;   // 0,16,32,48

    s16x8 pk0, pk1, pk2, pk3, pv00, pv01, pv10, pv11;
    auto load_tile = [&](int kbase) {
        const short* kp = qkv + (size_t)(b * Tt + kbase + krow) * QKV_N + Cc + h * Dd + kd0;
        pk0 = *(const s16x8*)kp;
        pk1 = *(const s16x8*)(kp + 8);
        pk2 = *(const s16x8*)(kp + 16);
        pk3 = *(const s16x8*)(kp + 24);
        const short* vp = qkv + (size_t)(b * Tt + kbase + key2) * QKV_N + 2 * Cc + h * Dd + dv0;
        pv00 = *(const s16x8*)vp;
        pv01 = *(const s16x8*)(vp + 8);
        pv10 = *(const s16x8*)(vp + QKV_N);
        pv11 = *(const s16x8*)(vp + QKV_N + 8);
    };
    auto store_tile = [&](int buf) {
        *(s16x8*)&Ks[buf][krow * KSP + kd0]      = pk0;
        *(s16x8*)&Ks[buf][krow * KSP + kd0 + 8]  = pk1;
        *(s16x8*)&Ks[buf][krow * KSP + kd0 + 16] = pk2;
        *(s16x8*)&Ks[buf][krow * KSP + kd0 + 24] = pk3;
#pragma unroll
        for (int j = 0; j < 8; j++) {
            ushort2 w; w.x = (unsigned short)pv00[j]; w.y = (unsigned short)pv10[j];
            *(ushort2*)&Vs[buf][(dv0 + j) * VSP + key2] = w;
        }
#pragma unroll
        for (int j = 0; j < 8; j++) {
            ushort2 w; w.x = (unsigned short)pv01[j]; w.y = (unsigned short)pv11[j];
            *(ushort2*)&Vs[buf][(dv0 + 8 + j) * VSP + key2] = w;
        }
    };

    auto process_pair = [&](int buf, int kbase, bool mask_a) {
        short* pwb = &Ks[buf ^ 1][wave * 32 * KSP];
        short* pwa = &Vs[buf ^ 1][wave * 32 * VSP];
        f32x4 eb[2][4], ea[2][4];
        __builtin_amdgcn_s_setprio(1);          // T5: QK^T MFMA cluster
#pragma unroll
        for (int g = 0; g < 4; g++) {
            s16x8 kf0 = *(const s16x8*)&Ks[buf][(g * 16 + l16) * KSP + quad * 8];
            s16x8 kf1 = *(const s16x8*)&Ks[buf][(g * 16 + l16) * KSP + 32 + quad * 8];
#pragma unroll
            for (int f = 0; f < 2; f++) {
                f32x4 zb = {}, za = {};
                zb = __builtin_amdgcn_mfma_f32_16x16x32_bf16(kf0, qfb[f][0], zb, 0, 0, 0);
                zb = __builtin_amdgcn_mfma_f32_16x16x32_bf16(kf1, qfb[f][1], zb, 0, 0, 0);
                za = __builtin_amdgcn_mfma_f32_16x16x32_bf16(kf0, qfa[f][0], za, 0, 0, 0);
                za = __builtin_amdgcn_mfma_f32_16x16x32_bf16(kf1, qfa[f][1], za, 0, 0, 0);
                eb[f][g] = zb; ea[f][g] = za;
            }
        }
        __builtin_amdgcn_s_setprio(0);
#pragma unroll
        for (int f = 0; f < 2; f++) {
            float rsb = 0.f, rsa = 0.f;
#pragma unroll
            for (int g = 0; g < 4; g++) {
#pragma unroll
                for (int r = 0; r < 4; r++) {
                    float pb = exp2f(eb[f][g][r]); rsb += pb; eb[f][g][r] = pb;
                    float pa = exp2f(ea[f][g][r]);
                    if (mask_a) pa = (kbase + g * 16 + quad * 4 + r <= q0a + f * 16 + l16) ? pa : 0.0f;
                    rsa += pa; ea[f][g][r] = pa;
                }
                uint2 ub, ua;
                ub.x = pkt(eb[f][g][1], eb[f][g][0]); ub.y = pkt(eb[f][g][3], eb[f][g][2]);
                ua.x = pkt(ea[f][g][1], ea[f][g][0]); ua.y = pkt(ea[f][g][3], ea[f][g][2]);
                *(uint2*)&pwb[(f * 16 + l16) * KSP + g * 16 + quad * 4] = ub;
                *(uint2*)&pwa[(f * 16 + l16) * VSP + g * 16 + quad * 4] = ua;
            }
            lb[f] += rsb; la[f] += rsa;
        }
        __builtin_amdgcn_s_setprio(1);          // T5: PV MFMA cluster
#pragma unroll
        for (int c = 0; c < 2; c++) {
            s16x8 vbf[4];
#pragma unroll
            for (int nc = 0; nc < 4; nc++)
                vbf[nc] = *(const s16x8*)&Vs[buf][(nc * 16 + l16) * VSP + c * 32 + quad * 8];
#pragma unroll
            for (int f = 0; f < 2; f++) {
                s16x8 pbb = *(const s16x8*)&pwb[(f * 16 + l16) * KSP + c * 32 + quad * 8];
                s16x8 pba = *(const s16x8*)&pwa[(f * 16 + l16) * VSP + c * 32 + quad * 8];
#pragma unroll
                for (int nc = 0; nc < 4; nc++) {
                    ob[f][nc] = __builtin_amdgcn_mfma_f32_16x16x32_bf16(vbf[nc], pbb, ob[f][nc], 0, 0, 0);
                    oa[f][nc] = __builtin_amdgcn_mfma_f32_16x16x32_bf16(vbf[nc], pba, oa[f][nc], 0, 0, 0);
                }
            }
        }
        __builtin_amdgcn_s_setprio(0);
    };

    auto process_single = [&](int buf, int kbase, bool masked) {
        short* pw = &Ks[buf ^ 1][wave * 32 * KSP];
        f32x4 e[2][4];
        __builtin_amdgcn_s_setprio(1);          // T5: QK^T MFMA cluster
#pragma unroll
        for (int g = 0; g < 4; g++) {
            s16x8 kf0 = *(const s16x8*)&Ks[buf][(g * 16 + l16) * KSP + quad * 8];
            s16x8 kf1 = *(const s16x8*)&Ks[buf][(g * 16 + l16) * KSP + 32 + quad * 8];
#pragma unroll
            for (int f = 0; f < 2; f++) {
                f32x4 z = {};
                z = __builtin_amdgcn_mfma_f32_16x16x32_bf16(kf0, qfb[f][0], z, 0, 0, 0);
                z = __builtin_amdgcn_mfma_f32_16x16x32_bf16(kf1, qfb[f][1], z, 0, 0, 0);
                e[f][g] = z;
            }
        }
        __builtin_amdgcn_s_setprio(0);
#pragma unroll
        for (int f = 0; f < 2; f++) {
            float rs = 0.f;
#pragma unroll
            for (int g = 0; g < 4; g++) {
#pragma unroll
                for (int r = 0; r < 4; r++) {
                    float p = exp2f(e[f][g][r]);
                    if (masked) p = (kbase + g * 16 + quad * 4 + r <= q0b + f * 16 + l16) ? p : 0.0f;
                    rs += p; e[f][g][r] = p;
                }
                uint2 u;
                u.x = pkt(e[f][g][1], e[f][g][0]); u.y = pkt(e[f][g][3], e[f][g][2]);
                *(uint2*)&pw[(f * 16 + l16) * KSP + g * 16 + quad * 4] = u;
            }
            lb[f] += rs;
        }
        __builtin_amdgcn_s_setprio(1);          // T5: PV MFMA cluster
#pragma unroll
        for (int c = 0; c < 2; c++) {
            s16x8 vbf[4];
#pragma unroll
            for (int nc = 0; nc < 4; nc++)
                vbf[nc] = *(const s16x8*)&Vs[buf][(nc * 16 + l16) * VSP + c * 32 + quad * 8];
#pragma unroll
            for (int f = 0; f < 2; f++) {
                s16x8 pb = *(const s16x8*)&pw[(f * 16 + l16) * KSP + c * 32 + quad * 8];
#pragma unroll
                for (int nc = 0; nc < 4; nc++)
                    ob[f][nc] = __builtin_amdgcn_mfma_f32_16x16x32_bf16(vbf[nc], pb, ob[f][nc], 0, 0, 0);
            }
        }
        __builtin_amdgcn_s_setprio(0);
    };

    load_tile(0);
    store_tile(0);
    for (int kt = 0; kt <= qb_blk; kt++) {
        __syncthreads();
        const int nb = (kt < qb_blk) ? (kt + 1) * 64 : qb_blk * 64;
        load_tile(nb);
        const int buf = kt & 1;
        const int kbase = kt * 64;
        if (kt <= qa_blk)
            process_pair(buf, kbase, kt == qa_blk);
        else
            process_single(buf, kbase, kt == qb_blk);
        store_tile(buf ^ 1);
    }

#pragma unroll
    for (int f = 0; f < 2; f++) {
        float sa = la[f]; sa += __shfl_xor(sa, 16, 64); sa += __shfl_xor(sa, 32, 64);
        float sb = lb[f]; sb += __shfl_xor(sb, 16, 64); sb += __shfl_xor(sb, 32, 64);
        const float inva = 1.0f / sa;
        const float invb = 1.0f / sb;
        short* ypa = y + (size_t)(b * Tt + q0a + f * 16 + l16) * Cc + h * Dd + quad * 4;
        short* ypb = y + (size_t)(b * Tt + q0b + f * 16 + l16) * Cc + h * Dd + quad * 4;
#pragma unroll
        for (int nc = 0; nc < 4; nc++) {
            s16x4 va, vb2;
#pragma unroll
            for (int r = 0; r < 4; r++) {
                va[r]  = f2bf(oa[f][nc][r] * inva);
                vb2[r] = f2bf(ob[f][nc][r] * invb);
            }
            *(s16x4*)&ypa[nc * 16] = va;
            *(s16x4*)&ypb[nc * 16] = vb2;
        }
    }
}

// ---------------------------------------------------------------------------
extern "C" void kernel_launch(void* const* d_in, const int* in_sizes, int n_in,
                              void* d_out, int out_size, void* d_ws, size_t ws_size,
                              hipStream_t stream) {
    const float* x      = (const float*)d_in[0];
    const float* w_qkv  = (const float*)d_in[1];
    const float* w_proj = (const float*)d_in[2];
    float* out = (float*)d_out;

    float2* cs    = (float2*)d_ws;                         // 1024*32 float2
    short* xb     = (short*)(cs + Tt * 32);                // 8192x768
    short* wqkvb  = xb + (size_t)M_ROWS * Cc;              // 2304x768 (sigma-permuted q/k rows)
    short* wprojb = wqkvb + (size_t)QKV_N * Cc;            // 768x768
    short* qkvb   = wprojb + (size_t)Cc * Cc;              // 8192x2304
    short* yb     = qkvb + (size_t)M_ROWS * QKV_N;         // 8192x768

    prep_kernel<<<PREP_THREADS / 256, 256, 0, stream>>>(
        x, w_qkv, w_proj, xb, wqkvb, wprojb, cs);

    // qkv = x @ w_qkv.T with fused RoPE + q-scale*log2e (bf16 out): 3/CU
    gemm_nt_mfma<1, 192><<<768, 256, 0, stream>>>(
        xb, wqkvb, qkvb, cs, M_ROWS, QKV_N, Cc, QKV_N / 192);

    // q-widened 2-wave attn: 768 blocks x 128 threads
    flash_attn<<<96 * 8, 128, 0, stream>>>(qkvb, yb);

    // out = y @ w_proj.T (fp32 out): 512 blocks = 2/CU exact, double-pumped
    gemm_nt_proj2<96><<<512, 256, 0, stream>>>(
        yb, wprojb, out, M_ROWS, Cc, Cc, Cc / 96);
}

// Round 8
// 167.129 us; speedup vs baseline: 1.1226x; 1.1226x over previous
//
#include <hip/hip_runtime.h>
#include <hip/hip_bf16.h>

// Problem constants (B,T,C,H) = (8,1024,768,12), D=64
#define Bb 8
#define Tt 1024
#define Cc 768
#define Hh 12
#define Dd 64
#define M_ROWS (Bb * Tt)      // 8192
#define QKV_N (3 * Cc)        // 2304

typedef __attribute__((ext_vector_type(8))) short s16x8;   // 8 x bf16
typedef __attribute__((ext_vector_type(4))) short s16x4;   // 4 x bf16
typedef __attribute__((ext_vector_type(4))) float f32x4;

#define AS1 __attribute__((address_space(1)))
#define AS3 __attribute__((address_space(3)))

static __device__ __forceinline__ short f2bf(float f) {
    union { float f; unsigned u; } v; v.f = f;
    unsigned r = (v.u + 0x7fffu + ((v.u >> 16) & 1u)) >> 16;  // RNE
    return (short)r;
}
// two f32 -> packed bf16x2 (TRUNCATION) in one v_perm_b32
static __device__ __forceinline__ unsigned pkt(float hi, float lo) {
    union { float f; unsigned u; } a, b; a.f = hi; b.f = lo;
    return __builtin_amdgcn_perm(a.u, b.u, 0x07060302u);
}

// ---------------------------------------------------------------------------
// Prep: fp32->bf16 casts + RoPE cos/sin table, one launch.
// wqkv rows are PERMUTED for q/k sections (sigma = row^0x30 for within-head
// quadrants 1,2): RoPE partners (i,i+32) become ADJACENT 16-col tiles in the
// qkv output, so any 32-col-aligned wave tile holds complete rotation pairs.
// Q.K is invariant (same sigma on q and k); v rows untouched.
// ---------------------------------------------------------------------------
static __device__ __forceinline__ void cast8(const float* __restrict__ in,
                                             short* __restrict__ out, int i) {
    const float4 a = ((const float4*)in)[i * 2];
    const float4 b = ((const float4*)in)[i * 2 + 1];
    s16x8 f;
    f[0] = f2bf(a.x); f[1] = f2bf(a.y); f[2] = f2bf(a.z); f[3] = f2bf(a.w);
    f[4] = f2bf(b.x); f[5] = f2bf(b.y); f[6] = f2bf(b.z); f[7] = f2bf(b.w);
    ((s16x8*)out)[i] = f;
}

#define S1 (M_ROWS * Cc / 8)   // 786432
#define S2 (QKV_N * Cc / 8)    // 221184
#define S3 (Cc * Cc / 8)       // 73728
#define SROPE (Tt * 32)        // 32768
#define PREP_THREADS (S1 + S2 + S3 + SROPE)  // 1114112 = 4352 * 256

__global__ __launch_bounds__(256) void prep_kernel(const float* __restrict__ x,
                                                   const float* __restrict__ wqkv,
                                                   const float* __restrict__ wproj,
                                                   short* __restrict__ xb,
                                                   short* __restrict__ wqkvb,
                                                   short* __restrict__ wprojb,
                                                   float2* __restrict__ cs) {
    int idx = blockIdx.x * blockDim.x + threadIdx.x;
    if (idx < S1) { cast8(x, xb, idx); return; }
    idx -= S1;
    if (idx < S2) {
        // permuted cast for wqkv: position-row n holds original row tau(n)
        int row = idx / 96;          // 768/8 = 96 chunks per row
        int c8  = idx - row * 96;
        int q2 = (row >> 4) & 3;
        int src = (row < 2 * Cc && (q2 == 1 || q2 == 2)) ? (row ^ 0x30) : row;
        const float4 a = ((const float4*)(wqkv + (size_t)src * Cc))[c8 * 2];
        const float4 b = ((const float4*)(wqkv + (size_t)src * Cc))[c8 * 2 + 1];
        s16x8 f;
        f[0] = f2bf(a.x); f[1] = f2bf(a.y); f[2] = f2bf(a.z); f[3] = f2bf(a.w);
        f[4] = f2bf(b.x); f[5] = f2bf(b.y); f[6] = f2bf(b.z); f[7] = f2bf(b.w);
        ((s16x8*)wqkvb)[idx] = f;
        return;
    }
    idx -= S2;
    if (idx < S3) { cast8(wproj, wprojb, idx); return; }
    idx -= S3;
    {
        int t = idx >> 5, i = idx & 31;
        float inv_freq = exp2f(-0.41524101186092037f * (float)i);  // log2(1e4)/32
        float fr = (float)t * inv_freq;
        float2 v; v.x = cosf(fr); v.y = sinf(fr);
        cs[idx] = v;
    }
}

// ---------------------------------------------------------------------------
// bf16 MFMA GEMM (NT): out[m][n] = sum_k A[m][k] * B[n][k]
// 128 x TN tile, BK=32, waves in 2x2 grid: each wave 64 rows x TN/2 cols.
// qkv TN=192 -> 768 blocks = 3/CU. Double-buffered global_load_lds pipeline
// (1 barrier/iter) + source-side XOR swizzle -> conflict-free ds_read_b128.
// XCD bm-stripe swizzle. MODE 1: bf16 out + fused RoPE epilogue.
// q-scale folds log2(e) (0.125*1.4426950408889634) so attn uses exp2f
// directly (one fewer v_mul per exp in the attn softmax; validated R7).
// NOTE (R1-R5 post-mortem): ALL deep-pipeline variants lost. GEMM
// pipelining on this kernel is permanently abandoned.
// NOTE (R7 post-mortem): attn q-widening (2-wave blocks) lost 45->58us:
// 2.48M LDS bank conflicts (2-thr/row K staging) + occupancy 13.7% (lost
// TLP for the serial softmax phase). Residency-driven overlap is what
// makes these kernels fast; do not trade waves for per-wave efficiency.
// ---------------------------------------------------------------------------
template <int MODE, int TN>
__global__ __launch_bounds__(256, 3) void gemm_nt_mfma(const short* __restrict__ A,
                                                       const short* __restrict__ B,
                                                       void* __restrict__ Cout,
                                                       const float2* __restrict__ cs,
                                                       int M, int N, int K, int nblocks) {
    __shared__ short As[2][128 * 32];
    __shared__ short Bs[2][TN * 32];
    constexpr int NTW = TN / 32;   // col-tiles per wave

    const int wave = threadIdx.x >> 6;
    const int lane = threadIdx.x & 63;
    const int l16  = lane & 15;
    const int quad = lane >> 4;
    const int wr = wave >> 1;      // 0,1 row half
    const int wc = wave & 1;       // 0,1 col half

    // XCD-aware swizzle (M/128 divisible by 8)
    const int mb8  = (M >> 7) >> 3;
    const int xcd  = blockIdx.x & 7;
    const int slot = blockIdx.x >> 3;
    const int bm = (xcd * mb8 + slot / nblocks) * 128;
    const int bn = (slot % nblocks) * TN;

    f32x4 acc[4][NTW] = {};

    auto stage = [&](int k0, int buf) {
#pragma unroll
        for (int j = 0; j < 2; j++) {                 // A: 512 chunks
            const int D = j * 256 + wave * 64 + lane;
            const int G = D >> 3;
            const int s = (G << 3) | ((D & 7) ^ (G & 7));
            const int m = s >> 2, c4 = (s & 3) * 8;
            __builtin_amdgcn_global_load_lds(
                (const AS1 unsigned*)(A + (size_t)(bm + m) * K + k0 + c4),
                (AS3 unsigned*)&As[buf][(j * 256 + wave * 64) * 8], 16, 0, 0);
        }
        constexpr int BCH = TN * 4;                   // B chunks
#pragma unroll
        for (int j = 0; j < (BCH + 255) / 256; j++) {
            if (BCH % 256 == 0 || j * 256 + wave * 64 < BCH) {  // wave-uniform
                const int D = j * 256 + wave * 64 + lane;
                const int G = D >> 3;
                const int s = (G << 3) | ((D & 7) ^ (G & 7));
                const int m = s >> 2, c4 = (s & 3) * 8;
                __builtin_amdgcn_global_load_lds(
                    (const AS1 unsigned*)(B + (size_t)(bn + m) * K + k0 + c4),
                    (AS3 unsigned*)&Bs[buf][(j * 256 + wave * 64) * 8], 16, 0, 0);
            }
        }
    };

    const int nIter = K >> 5;   // K/32
    stage(0, 0);
    for (int kt = 0; kt < nIter; kt++) {
        const int buf = kt & 1;
        __syncthreads();                       // drains loads for tile kt
        if (kt + 1 < nIter) stage((kt + 1) << 5, buf ^ 1);

        s16x8 af[4];
#pragma unroll
        for (int mt = 0; mt < 4; mt++) {
            const int m = wr * 64 + mt * 16 + l16;
            const int d = ((m & 1) * 4 + quad) ^ ((m >> 1) & 7);
            af[mt] = *(const s16x8*)&As[buf][(m >> 1) * 64 + d * 8];
        }
#pragma unroll
        for (int nt = 0; nt < NTW; nt++) {
            const int n = wc * (TN / 2) + nt * 16 + l16;
            const int d = ((n & 1) * 4 + quad) ^ ((n >> 1) & 7);
            s16x8 bf = *(const s16x8*)&Bs[buf][(n >> 1) * 64 + d * 8];
#pragma unroll
            for (int mt = 0; mt < 4; mt++)
                acc[mt][nt] = __builtin_amdgcn_mfma_f32_16x16x32_bf16(
                    af[mt], bf, acc[mt][nt], 0, 0, 0);
        }
    }

    if constexpr (MODE == 0) {
#pragma unroll
        for (int mt = 0; mt < 4; mt++)
#pragma unroll
            for (int r = 0; r < 4; r++) {
                const size_t row = bm + wr * 64 + mt * 16 + quad * 4 + r;
#pragma unroll
                for (int nt = 0; nt < NTW; nt++)
                    ((float*)Cout)[row * N + bn + wc * (TN / 2) + nt * 16 + l16] =
                        acc[mt][nt][r];
            }
    } else {
        const bool is_v = (bn >= 2 * Cc);
        if (is_v) {
#pragma unroll
            for (int mt = 0; mt < 4; mt++)
#pragma unroll
                for (int r = 0; r < 4; r++) {
                    const size_t row = bm + wr * 64 + mt * 16 + quad * 4 + r;
#pragma unroll
                    for (int nt = 0; nt < NTW; nt++)
                        ((short*)Cout)[row * N + bn + wc * (TN / 2) + nt * 16 + l16] =
                            f2bf(acc[mt][nt][r]);
                }
        } else {
            // q gets 1/sqrt(D) * log2(e) = 0.125 * 1.4426950408889634
            const float scale = (bn < Cc) ? 0.18033688511112043f : 1.0f;
#pragma unroll
            for (int mt = 0; mt < 4; mt++) {
#pragma unroll
                for (int r = 0; r < 4; r++) {
                    const int row = bm + wr * 64 + mt * 16 + quad * 4 + r;
                    const int t = row & (Tt - 1);
                    short* cp = (short*)Cout + (size_t)row * N + bn + wc * (TN / 2);
#pragma unroll
                    for (int p = 0; p < NTW; p += 2) {   // adjacent-tile pairs
                        const int g = wc * NTW + p;       // global col-tile (even)
                        const int i0 = ((g & 2) ? 16 : 0) + l16;
                        const float2 c0 = cs[t * 32 + i0];
                        const float x1 = acc[mt][p][r];
                        const float x2 = acc[mt][p + 1][r];
                        cp[p * 16 + l16]        = f2bf((x1 * c0.x + x2 * c0.y) * scale);
                        cp[(p + 1) * 16 + l16]  = f2bf((-x1 * c0.y + x2 * c0.x) * scale);
                    }
                }
            }
        }
    }
}

// ---------------------------------------------------------------------------
// PROJ GEMM, double-pumped K-loop (R6, kept: neutral-to-slightly-positive):
//   stage TWO BK=32 tiles per round (4 bufs, 56 KB, 2 blocks/CU), ONE
//   __syncthreads per 2 tiles -> 12 rounds. MODE 0 epilogue (fp32 out).
// ---------------------------------------------------------------------------
template <int TN>
__global__ __launch_bounds__(256, 2) void gemm_nt_proj2(const short* __restrict__ A,
                                                        const short* __restrict__ B,
                                                        float* __restrict__ Cout,
                                                        int M, int N, int K, int nblocks) {
    __shared__ short As[2][2][128 * 32];   // [pair][tile]
    __shared__ short Bs[2][2][TN * 32];
    constexpr int NTW = TN / 32;   // col-tiles per wave

    const int wave = threadIdx.x >> 6;
    const int lane = threadIdx.x & 63;
    const int l16  = lane & 15;
    const int quad = lane >> 4;
    const int wr = wave >> 1;      // 0,1 row half
    const int wc = wave & 1;       // 0,1 col half

    // XCD-aware swizzle (M/128 divisible by 8)
    const int mb8  = (M >> 7) >> 3;
    const int xcd  = blockIdx.x & 7;
    const int slot = blockIdx.x >> 3;
    const int bm = (xcd * mb8 + slot / nblocks) * 128;
    const int bn = (slot % nblocks) * TN;

    f32x4 acc[4][NTW] = {};

    auto stage = [&](int k0, int p, int t) {
#pragma unroll
        for (int j = 0; j < 2; j++) {                 // A: 512 chunks
            const int D = j * 256 + wave * 64 + lane;
            const int G = D >> 3;
            const int s = (G << 3) | ((D & 7) ^ (G & 7));
            const int m = s >> 2, c4 = (s & 3) * 8;
            __builtin_amdgcn_global_load_lds(
                (const AS1 unsigned*)(A + (size_t)(bm + m) * K + k0 + c4),
                (AS3 unsigned*)&As[p][t][(j * 256 + wave * 64) * 8], 16, 0, 0);
        }
        constexpr int BCH = TN * 4;                   // B chunks
#pragma unroll
        for (int j = 0; j < (BCH + 255) / 256; j++) {
            if (BCH % 256 == 0 || j * 256 + wave * 64 < BCH) {  // wave-uniform
                const int D = j * 256 + wave * 64 + lane;
                const int G = D >> 3;
                const int s = (G << 3) | ((D & 7) ^ (G & 7));
                const int m = s >> 2, c4 = (s & 3) * 8;
                __builtin_amdgcn_global_load_lds(
                    (const AS1 unsigned*)(B + (size_t)(bn + m) * K + k0 + c4),
                    (AS3 unsigned*)&Bs[p][t][(j * 256 + wave * 64) * 8], 16, 0, 0);
            }
        }
    };

    const int nPair = K >> 6;   // K/64 double-rounds (768 -> 12)
    stage(0, 0, 0);
    stage(32, 0, 1);
    for (int it = 0; it < nPair; it++) {
        const int p = it & 1;
        __syncthreads();                       // drains both tiles of pair it
        if (it + 1 < nPair) {
            stage((2 * it + 2) << 5, p ^ 1, 0);
            stage((2 * it + 3) << 5, p ^ 1, 1);
        }
#pragma unroll
        for (int t = 0; t < 2; t++) {
            s16x8 af[4];
#pragma unroll
            for (int mt = 0; mt < 4; mt++) {
                const int m = wr * 64 + mt * 16 + l16;
                const int d = ((m & 1) * 4 + quad) ^ ((m >> 1) & 7);
                af[mt] = *(const s16x8*)&As[p][t][(m >> 1) * 64 + d * 8];
            }
#pragma unroll
            for (int nt = 0; nt < NTW; nt++) {
                const int n = wc * (TN / 2) + nt * 16 + l16;
                const int d = ((n & 1) * 4 + quad) ^ ((n >> 1) & 7);
                s16x8 bf = *(const s16x8*)&Bs[p][t][(n >> 1) * 64 + d * 8];
#pragma unroll
                for (int mt = 0; mt < 4; mt++)
                    acc[mt][nt] = __builtin_amdgcn_mfma_f32_16x16x32_bf16(
                        af[mt], bf, acc[mt][nt], 0, 0, 0);
            }
        }
    }

#pragma unroll
    for (int mt = 0; mt < 4; mt++)
#pragma unroll
        for (int r = 0; r < 4; r++) {
            const size_t row = bm + wr * 64 + mt * 16 + quad * 4 + r;
#pragma unroll
            for (int nt = 0; nt < NTW; nt++)
                Cout[row * N + bn + wc * (TN / 2) + nt * 16 + l16] = acc[mt][nt][r];
        }
}

// ---------------------------------------------------------------------------
// Flash attention v3 (S^T formulation) — R6 structure (proven 4-wave/256t):
//   - process_pair fuses both q-tiles on shared K/V fragment reads.
//   - P converted with v_perm_b32 packed truncation.
//   - P scratch aliases this wave's own store rows: qb in Ks[buf^1],
//     qa in Vs[buf^1].
// Complementary q-block pairing: 768 equal blocks = 3/CU.
// T5 setprio around MFMA clusters (R4 banked win).
// R8: exp2f with log2e pre-folded into q-scale (saves one v_mul per exp
// in the serial softmax VALU phase; structure unchanged).
// ---------------------------------------------------------------------------
#define KSP 72
#define VSP 72

__global__ __launch_bounds__(256, 3) void flash_attn(const short* __restrict__ qkv,
                                                     short* __restrict__ y) {
    __shared__ short Ks[2][64 * KSP];
    __shared__ short Vs[2][64 * VSP];

    const int wave = threadIdx.x >> 6;
    const int lane = threadIdx.x & 63;
    const int l16  = lane & 15;
    const int quad = lane >> 4;

    const int pair = blockIdx.x / 96;     // 0..7
    const int bh   = blockIdx.x % 96;
    const int h = bh % Hh;
    const int b = bh / Hh;
    const int qa_blk = pair;
    const int qb_blk = 15 - pair;
    const int q0a = qa_blk * 64 + wave * 16;
    const int q0b = qb_blk * 64 + wave * 16;

    s16x8 qfa[2], qfb[2];
    {
        const short* qpa = qkv + (size_t)(b * Tt + q0a + l16) * QKV_N + h * Dd + quad * 8;
        const short* qpb = qkv + (size_t)(b * Tt + q0b + l16) * QKV_N + h * Dd + quad * 8;
        qfa[0] = *(const s16x8*)qpa;  qfa[1] = *(const s16x8*)(qpa + 32);
        qfb[0] = *(const s16x8*)qpb;  qfb[1] = *(const s16x8*)(qpb + 32);
    }

    f32x4 oa[4] = {}, ob[4] = {};
    float la = 0.f, lb = 0.f;

    const int krow = threadIdx.x >> 2;
    const int kd0  = (threadIdx.x & 3) * 16;
    const int key2 = (threadIdx.x & 31) * 2;
    const int dv0  = (threadIdx.x >> 5) * 8;

    s16x8 pk0, pk1, pv0, pv1;
    auto load_tile = [&](int kbase) {
        const short* kp = qkv + (size_t)(b * Tt + kbase + krow) * QKV_N + Cc + h * Dd + kd0;
        pk0 = *(const s16x8*)kp;
        pk1 = *(const s16x8*)(kp + 8);
        const short* vp = qkv + (size_t)(b * Tt + kbase + key2) * QKV_N + 2 * Cc + h * Dd + dv0;
        pv0 = *(const s16x8*)vp;
        pv1 = *(const s16x8*)(vp + QKV_N);
    };
    auto store_tile = [&](int buf) {
        *(s16x8*)&Ks[buf][krow * KSP + kd0]     = pk0;
        *(s16x8*)&Ks[buf][krow * KSP + kd0 + 8] = pk1;
#pragma unroll
        for (int j = 0; j < 8; j++) {
            ushort2 w; w.x = (unsigned short)pv0[j]; w.y = (unsigned short)pv1[j];
            *(ushort2*)&Vs[buf][(dv0 + j) * VSP + key2] = w;
        }
    };

    auto process_pair = [&](int buf, int kbase, bool mask_a) {
        short* pwb = &Ks[buf ^ 1][wave * 16 * KSP];
        short* pwa = &Vs[buf ^ 1][wave * 16 * VSP];
        f32x4 eb[4], ea[4];
        __builtin_amdgcn_s_setprio(1);          // T5: QK^T MFMA cluster
#pragma unroll
        for (int g = 0; g < 4; g++) {
            s16x8 kf0 = *(const s16x8*)&Ks[buf][(g * 16 + l16) * KSP + quad * 8];
            s16x8 kf1 = *(const s16x8*)&Ks[buf][(g * 16 + l16) * KSP + 32 + quad * 8];
            f32x4 zb = {}, za = {};
            zb = __builtin_amdgcn_mfma_f32_16x16x32_bf16(kf0, qfb[0], zb, 0, 0, 0);
            zb = __builtin_amdgcn_mfma_f32_16x16x32_bf16(kf1, qfb[1], zb, 0, 0, 0);
            za = __builtin_amdgcn_mfma_f32_16x16x32_bf16(kf0, qfa[0], za, 0, 0, 0);
            za = __builtin_amdgcn_mfma_f32_16x16x32_bf16(kf1, qfa[1], za, 0, 0, 0);
            eb[g] = zb; ea[g] = za;
        }
        __builtin_amdgcn_s_setprio(0);
        float rsb = 0.f, rsa = 0.f;
#pragma unroll
        for (int g = 0; g < 4; g++) {
#pragma unroll
            for (int r = 0; r < 4; r++) {
                float pb = exp2f(eb[g][r]); rsb += pb; eb[g][r] = pb;
                float pa = exp2f(ea[g][r]);
                if (mask_a) pa = (kbase + g * 16 + quad * 4 + r <= q0a + l16) ? pa : 0.0f;
                rsa += pa; ea[g][r] = pa;
            }
            uint2 ub, ua;
            ub.x = pkt(eb[g][1], eb[g][0]); ub.y = pkt(eb[g][3], eb[g][2]);
            ua.x = pkt(ea[g][1], ea[g][0]); ua.y = pkt(ea[g][3], ea[g][2]);
            *(uint2*)&pwb[l16 * KSP + g * 16 + quad * 4] = ub;
            *(uint2*)&pwa[l16 * VSP + g * 16 + quad * 4] = ua;
        }
        lb += rsb; la += rsa;
        __builtin_amdgcn_s_setprio(1);          // T5: PV MFMA cluster
#pragma unroll
        for (int c = 0; c < 2; c++) {
            s16x8 pbb = *(const s16x8*)&pwb[l16 * KSP + c * 32 + quad * 8];
            s16x8 pba = *(const s16x8*)&pwa[l16 * VSP + c * 32 + quad * 8];
#pragma unroll
            for (int nc = 0; nc < 4; nc++) {
                s16x8 vb = *(const s16x8*)&Vs[buf][(nc * 16 + l16) * VSP + c * 32 + quad * 8];
                ob[nc] = __builtin_amdgcn_mfma_f32_16x16x32_bf16(vb, pbb, ob[nc], 0, 0, 0);
                oa[nc] = __builtin_amdgcn_mfma_f32_16x16x32_bf16(vb, pba, oa[nc], 0, 0, 0);
            }
        }
        __builtin_amdgcn_s_setprio(0);
    };

    auto process_single = [&](int buf, int kbase, bool masked) {
        short* pw = &Ks[buf ^ 1][wave * 16 * KSP];
        f32x4 e[4];
        __builtin_amdgcn_s_setprio(1);          // T5: QK^T MFMA cluster
#pragma unroll
        for (int g = 0; g < 4; g++) {
            s16x8 kf0 = *(const s16x8*)&Ks[buf][(g * 16 + l16) * KSP + quad * 8];
            s16x8 kf1 = *(const s16x8*)&Ks[buf][(g * 16 + l16) * KSP + 32 + quad * 8];
            f32x4 z = {};
            z = __builtin_amdgcn_mfma_f32_16x16x32_bf16(kf0, qfb[0], z, 0, 0, 0);
            z = __builtin_amdgcn_mfma_f32_16x16x32_bf16(kf1, qfb[1], z, 0, 0, 0);
            e[g] = z;
        }
        __builtin_amdgcn_s_setprio(0);
        float rs = 0.f;
#pragma unroll
        for (int g = 0; g < 4; g++) {
#pragma unroll
            for (int r = 0; r < 4; r++) {
                float p = exp2f(e[g][r]);
                if (masked) p = (kbase + g * 16 + quad * 4 + r <= q0b + l16) ? p : 0.0f;
                rs += p; e[g][r] = p;
            }
            uint2 u;
            u.x = pkt(e[g][1], e[g][0]); u.y = pkt(e[g][3], e[g][2]);
            *(uint2*)&pw[l16 * KSP + g * 16 + quad * 4] = u;
        }
        lb += rs;
        __builtin_amdgcn_s_setprio(1);          // T5: PV MFMA cluster
#pragma unroll
        for (int c = 0; c < 2; c++) {
            s16x8 pb = *(const s16x8*)&pw[l16 * KSP + c * 32 + quad * 8];
#pragma unroll
            for (int nc = 0; nc < 4; nc++) {
                s16x8 vb = *(const s16x8*)&Vs[buf][(nc * 16 + l16) * VSP + c * 32 + quad * 8];
                ob[nc] = __builtin_amdgcn_mfma_f32_16x16x32_bf16(vb, pb, ob[nc], 0, 0, 0);
            }
        }
        __builtin_amdgcn_s_setprio(0);
    };

    load_tile(0);
    store_tile(0);
    for (int kt = 0; kt <= qb_blk; kt++) {
        __syncthreads();
        const int nb = (kt < qb_blk) ? (kt + 1) * 64 : qb_blk * 64;
        load_tile(nb);
        const int buf = kt & 1;
        const int kbase = kt * 64;
        if (kt <= qa_blk)
            process_pair(buf, kbase, kt == qa_blk);
        else
            process_single(buf, kbase, kt == qb_blk);
        store_tile(buf ^ 1);
    }

    float sa = la; sa += __shfl_xor(sa, 16, 64); sa += __shfl_xor(sa, 32, 64);
    float sb = lb; sb += __shfl_xor(sb, 16, 64); sb += __shfl_xor(sb, 32, 64);
    const float inva = 1.0f / sa;
    const float invb = 1.0f / sb;
    short* ypa = y + (size_t)(b * Tt + q0a + l16) * Cc + h * Dd + quad * 4;
    short* ypb = y + (size_t)(b * Tt + q0b + l16) * Cc + h * Dd + quad * 4;
#pragma unroll
    for (int nc = 0; nc < 4; nc++) {
        s16x4 va, vb2;
#pragma unroll
        for (int r = 0; r < 4; r++) {
            va[r]  = f2bf(oa[nc][r] * inva);
            vb2[r] = f2bf(ob[nc][r] * invb);
        }
        *(s16x4*)&ypa[nc * 16] = va;
        *(s16x4*)&ypb[nc * 16] = vb2;
    }
}

// ---------------------------------------------------------------------------
extern "C" void kernel_launch(void* const* d_in, const int* in_sizes, int n_in,
                              void* d_out, int out_size, void* d_ws, size_t ws_size,
                              hipStream_t stream) {
    const float* x      = (const float*)d_in[0];
    const float* w_qkv  = (const float*)d_in[1];
    const float* w_proj = (const float*)d_in[2];
    float* out = (float*)d_out;

    float2* cs    = (float2*)d_ws;                         // 1024*32 float2
    short* xb     = (short*)(cs + Tt * 32);                // 8192x768
    short* wqkvb  = xb + (size_t)M_ROWS * Cc;              // 2304x768 (sigma-permuted q/k rows)
    short* wprojb = wqkvb + (size_t)QKV_N * Cc;            // 768x768
    short* qkvb   = wprojb + (size_t)Cc * Cc;              // 8192x2304
    short* yb     = qkvb + (size_t)M_ROWS * QKV_N;         // 8192x768

    prep_kernel<<<PREP_THREADS / 256, 256, 0, stream>>>(
        x, w_qkv, w_proj, xb, wqkvb, wprojb, cs);

    // qkv = x @ w_qkv.T with fused RoPE + q-scale*log2e (bf16 out): 3/CU
    gemm_nt_mfma<1, 192><<<768, 256, 0, stream>>>(
        xb, wqkvb, qkvb, cs, M_ROWS, QKV_N, Cc, QKV_N / 192);

    flash_attn<<<96 * 8, 256, 0, stream>>>(qkvb, yb);

    // out = y @ w_proj.T (fp32 out): 512 blocks = 2/CU exact, double-pumped
    gemm_nt_proj2<96><<<512, 256, 0, stream>>>(
        yb, wprojb, out, M_ROWS, Cc, Cc, Cc / 96);
}

// Round 9
// 163.800 us; speedup vs baseline: 1.1454x; 1.0203x over previous
//
#include <hip/hip_runtime.h>
#include <hip/hip_bf16.h>

// Problem constants (B,T,C,H) = (8,1024,768,12), D=64
#define Bb 8
#define Tt 1024
#define Cc 768
#define Hh 12
#define Dd 64
#define M_ROWS (Bb * Tt)      // 8192
#define QKV_N (3 * Cc)        // 2304

typedef __attribute__((ext_vector_type(8))) short s16x8;   // 8 x bf16
typedef __attribute__((ext_vector_type(4))) short s16x4;   // 4 x bf16
typedef __attribute__((ext_vector_type(4))) float f32x4;

#define AS1 __attribute__((address_space(1)))
#define AS3 __attribute__((address_space(3)))

static __device__ __forceinline__ short f2bf(float f) {
    union { float f; unsigned u; } v; v.f = f;
    unsigned r = (v.u + 0x7fffu + ((v.u >> 16) & 1u)) >> 16;  // RNE
    return (short)r;
}
// two f32 -> packed bf16x2 (TRUNCATION) in one v_perm_b32
static __device__ __forceinline__ unsigned pkt(float hi, float lo) {
    union { float f; unsigned u; } a, b; a.f = hi; b.f = lo;
    return __builtin_amdgcn_perm(a.u, b.u, 0x07060302u);
}
// raw v_exp_f32: D = 2^x, ONE transcendental op.
// R8 post-mortem: libm exp2f lowers to __ocml_exp2_f32 (precise path, extra
// edge-case ops) and cost +4.7us; __expf is v_mul+v_exp. This is the true
// single-instruction path for the pre-folded-log2e scores.
static __device__ __forceinline__ float fexp2(float x) {
    float r;
    asm("v_exp_f32 %0, %1" : "=v"(r) : "v"(x));
    return r;
}

// ---------------------------------------------------------------------------
// Prep: fp32->bf16 casts + RoPE cos/sin table, one launch.
// wqkv rows are PERMUTED for q/k sections (sigma = row^0x30 for within-head
// quadrants 1,2): RoPE partners (i,i+32) become ADJACENT 16-col tiles in the
// qkv output, so any 32-col-aligned wave tile holds complete rotation pairs.
// Q.K is invariant (same sigma on q and k); v rows untouched.
// ---------------------------------------------------------------------------
static __device__ __forceinline__ void cast8(const float* __restrict__ in,
                                             short* __restrict__ out, int i) {
    const float4 a = ((const float4*)in)[i * 2];
    const float4 b = ((const float4*)in)[i * 2 + 1];
    s16x8 f;
    f[0] = f2bf(a.x); f[1] = f2bf(a.y); f[2] = f2bf(a.z); f[3] = f2bf(a.w);
    f[4] = f2bf(b.x); f[5] = f2bf(b.y); f[6] = f2bf(b.z); f[7] = f2bf(b.w);
    ((s16x8*)out)[i] = f;
}

#define S1 (M_ROWS * Cc / 8)   // 786432
#define S2 (QKV_N * Cc / 8)    // 221184
#define S3 (Cc * Cc / 8)       // 73728
#define SROPE (Tt * 32)        // 32768
#define PREP_THREADS (S1 + S2 + S3 + SROPE)  // 1114112 = 4352 * 256

__global__ __launch_bounds__(256) void prep_kernel(const float* __restrict__ x,
                                                   const float* __restrict__ wqkv,
                                                   const float* __restrict__ wproj,
                                                   short* __restrict__ xb,
                                                   short* __restrict__ wqkvb,
                                                   short* __restrict__ wprojb,
                                                   float2* __restrict__ cs) {
    int idx = blockIdx.x * blockDim.x + threadIdx.x;
    if (idx < S1) { cast8(x, xb, idx); return; }
    idx -= S1;
    if (idx < S2) {
        // permuted cast for wqkv: position-row n holds original row tau(n)
        int row = idx / 96;          // 768/8 = 96 chunks per row
        int c8  = idx - row * 96;
        int q2 = (row >> 4) & 3;
        int src = (row < 2 * Cc && (q2 == 1 || q2 == 2)) ? (row ^ 0x30) : row;
        const float4 a = ((const float4*)(wqkv + (size_t)src * Cc))[c8 * 2];
        const float4 b = ((const float4*)(wqkv + (size_t)src * Cc))[c8 * 2 + 1];
        s16x8 f;
        f[0] = f2bf(a.x); f[1] = f2bf(a.y); f[2] = f2bf(a.z); f[3] = f2bf(a.w);
        f[4] = f2bf(b.x); f[5] = f2bf(b.y); f[6] = f2bf(b.z); f[7] = f2bf(b.w);
        ((s16x8*)wqkvb)[idx] = f;
        return;
    }
    idx -= S2;
    if (idx < S3) { cast8(wproj, wprojb, idx); return; }
    idx -= S3;
    {
        int t = idx >> 5, i = idx & 31;
        float inv_freq = exp2f(-0.41524101186092037f * (float)i);  // log2(1e4)/32
        float fr = (float)t * inv_freq;
        float2 v; v.x = cosf(fr); v.y = sinf(fr);
        cs[idx] = v;
    }
}

// ---------------------------------------------------------------------------
// bf16 MFMA GEMM (NT): out[m][n] = sum_k A[m][k] * B[n][k]
// 128 x TN tile, BK=32, waves in 2x2 grid: each wave 64 rows x TN/2 cols.
// qkv TN=192 -> 768 blocks = 3/CU. Double-buffered global_load_lds pipeline
// (1 barrier/iter) + source-side XOR swizzle -> conflict-free ds_read_b128.
// XCD bm-stripe swizzle. MODE 1: bf16 out + fused RoPE epilogue.
// q-scale folds log2(e) (0.125*1.4426950408889634); attn uses raw v_exp_f32.
// NOTE (R1-R5): ALL deep-pipeline variants lost; pipelining abandoned.
// NOTE (R7): attn q-widening lost (bank conflicts + occupancy); residency-
// driven overlap is what makes these kernels fast.
// NOTE (R8): libm exp2f is the PRECISE ocml path (+4.7us); use raw v_exp.
// ---------------------------------------------------------------------------
template <int MODE, int TN>
__global__ __launch_bounds__(256, 3) void gemm_nt_mfma(const short* __restrict__ A,
                                                       const short* __restrict__ B,
                                                       void* __restrict__ Cout,
                                                       const float2* __restrict__ cs,
                                                       int M, int N, int K, int nblocks) {
    __shared__ short As[2][128 * 32];
    __shared__ short Bs[2][TN * 32];
    constexpr int NTW = TN / 32;   // col-tiles per wave

    const int wave = threadIdx.x >> 6;
    const int lane = threadIdx.x & 63;
    const int l16  = lane & 15;
    const int quad = lane >> 4;
    const int wr = wave >> 1;      // 0,1 row half
    const int wc = wave & 1;       // 0,1 col half

    // XCD-aware swizzle (M/128 divisible by 8)
    const int mb8  = (M >> 7) >> 3;
    const int xcd  = blockIdx.x & 7;
    const int slot = blockIdx.x >> 3;
    const int bm = (xcd * mb8 + slot / nblocks) * 128;
    const int bn = (slot % nblocks) * TN;

    f32x4 acc[4][NTW] = {};

    auto stage = [&](int k0, int buf) {
#pragma unroll
        for (int j = 0; j < 2; j++) {                 // A: 512 chunks
            const int D = j * 256 + wave * 64 + lane;
            const int G = D >> 3;
            const int s = (G << 3) | ((D & 7) ^ (G & 7));
            const int m = s >> 2, c4 = (s & 3) * 8;
            __builtin_amdgcn_global_load_lds(
                (const AS1 unsigned*)(A + (size_t)(bm + m) * K + k0 + c4),
                (AS3 unsigned*)&As[buf][(j * 256 + wave * 64) * 8], 16, 0, 0);
        }
        constexpr int BCH = TN * 4;                   // B chunks
#pragma unroll
        for (int j = 0; j < (BCH + 255) / 256; j++) {
            if (BCH % 256 == 0 || j * 256 + wave * 64 < BCH) {  // wave-uniform
                const int D = j * 256 + wave * 64 + lane;
                const int G = D >> 3;
                const int s = (G << 3) | ((D & 7) ^ (G & 7));
                const int m = s >> 2, c4 = (s & 3) * 8;
                __builtin_amdgcn_global_load_lds(
                    (const AS1 unsigned*)(B + (size_t)(bn + m) * K + k0 + c4),
                    (AS3 unsigned*)&Bs[buf][(j * 256 + wave * 64) * 8], 16, 0, 0);
            }
        }
    };

    const int nIter = K >> 5;   // K/32
    stage(0, 0);
    for (int kt = 0; kt < nIter; kt++) {
        const int buf = kt & 1;
        __syncthreads();                       // drains loads for tile kt
        if (kt + 1 < nIter) stage((kt + 1) << 5, buf ^ 1);

        s16x8 af[4];
#pragma unroll
        for (int mt = 0; mt < 4; mt++) {
            const int m = wr * 64 + mt * 16 + l16;
            const int d = ((m & 1) * 4 + quad) ^ ((m >> 1) & 7);
            af[mt] = *(const s16x8*)&As[buf][(m >> 1) * 64 + d * 8];
        }
#pragma unroll
        for (int nt = 0; nt < NTW; nt++) {
            const int n = wc * (TN / 2) + nt * 16 + l16;
            const int d = ((n & 1) * 4 + quad) ^ ((n >> 1) & 7);
            s16x8 bf = *(const s16x8*)&Bs[buf][(n >> 1) * 64 + d * 8];
#pragma unroll
            for (int mt = 0; mt < 4; mt++)
                acc[mt][nt] = __builtin_amdgcn_mfma_f32_16x16x32_bf16(
                    af[mt], bf, acc[mt][nt], 0, 0, 0);
        }
    }

    if constexpr (MODE == 0) {
#pragma unroll
        for (int mt = 0; mt < 4; mt++)
#pragma unroll
            for (int r = 0; r < 4; r++) {
                const size_t row = bm + wr * 64 + mt * 16 + quad * 4 + r;
#pragma unroll
                for (int nt = 0; nt < NTW; nt++)
                    ((float*)Cout)[row * N + bn + wc * (TN / 2) + nt * 16 + l16] =
                        acc[mt][nt][r];
            }
    } else {
        const bool is_v = (bn >= 2 * Cc);
        if (is_v) {
#pragma unroll
            for (int mt = 0; mt < 4; mt++)
#pragma unroll
                for (int r = 0; r < 4; r++) {
                    const size_t row = bm + wr * 64 + mt * 16 + quad * 4 + r;
#pragma unroll
                    for (int nt = 0; nt < NTW; nt++)
                        ((short*)Cout)[row * N + bn + wc * (TN / 2) + nt * 16 + l16] =
                            f2bf(acc[mt][nt][r]);
                }
        } else {
            // q gets 1/sqrt(D) * log2(e) = 0.125 * 1.4426950408889634
            const float scale = (bn < Cc) ? 0.18033688511112043f : 1.0f;
#pragma unroll
            for (int mt = 0; mt < 4; mt++) {
#pragma unroll
                for (int r = 0; r < 4; r++) {
                    const int row = bm + wr * 64 + mt * 16 + quad * 4 + r;
                    const int t = row & (Tt - 1);
                    short* cp = (short*)Cout + (size_t)row * N + bn + wc * (TN / 2);
#pragma unroll
                    for (int p = 0; p < NTW; p += 2) {   // adjacent-tile pairs
                        const int g = wc * NTW + p;       // global col-tile (even)
                        const int i0 = ((g & 2) ? 16 : 0) + l16;
                        const float2 c0 = cs[t * 32 + i0];
                        const float x1 = acc[mt][p][r];
                        const float x2 = acc[mt][p + 1][r];
                        cp[p * 16 + l16]        = f2bf((x1 * c0.x + x2 * c0.y) * scale);
                        cp[(p + 1) * 16 + l16]  = f2bf((-x1 * c0.y + x2 * c0.x) * scale);
                    }
                }
            }
        }
    }
}

// ---------------------------------------------------------------------------
// PROJ GEMM, double-pumped K-loop (R6, kept: neutral-to-slightly-positive):
//   stage TWO BK=32 tiles per round (4 bufs, 56 KB, 2 blocks/CU), ONE
//   __syncthreads per 2 tiles -> 12 rounds. MODE 0 epilogue (fp32 out).
// ---------------------------------------------------------------------------
template <int TN>
__global__ __launch_bounds__(256, 2) void gemm_nt_proj2(const short* __restrict__ A,
                                                        const short* __restrict__ B,
                                                        float* __restrict__ Cout,
                                                        int M, int N, int K, int nblocks) {
    __shared__ short As[2][2][128 * 32];   // [pair][tile]
    __shared__ short Bs[2][2][TN * 32];
    constexpr int NTW = TN / 32;   // col-tiles per wave

    const int wave = threadIdx.x >> 6;
    const int lane = threadIdx.x & 63;
    const int l16  = lane & 15;
    const int quad = lane >> 4;
    const int wr = wave >> 1;      // 0,1 row half
    const int wc = wave & 1;       // 0,1 col half

    // XCD-aware swizzle (M/128 divisible by 8)
    const int mb8  = (M >> 7) >> 3;
    const int xcd  = blockIdx.x & 7;
    const int slot = blockIdx.x >> 3;
    const int bm = (xcd * mb8 + slot / nblocks) * 128;
    const int bn = (slot % nblocks) * TN;

    f32x4 acc[4][NTW] = {};

    auto stage = [&](int k0, int p, int t) {
#pragma unroll
        for (int j = 0; j < 2; j++) {                 // A: 512 chunks
            const int D = j * 256 + wave * 64 + lane;
            const int G = D >> 3;
            const int s = (G << 3) | ((D & 7) ^ (G & 7));
            const int m = s >> 2, c4 = (s & 3) * 8;
            __builtin_amdgcn_global_load_lds(
                (const AS1 unsigned*)(A + (size_t)(bm + m) * K + k0 + c4),
                (AS3 unsigned*)&As[p][t][(j * 256 + wave * 64) * 8], 16, 0, 0);
        }
        constexpr int BCH = TN * 4;                   // B chunks
#pragma unroll
        for (int j = 0; j < (BCH + 255) / 256; j++) {
            if (BCH % 256 == 0 || j * 256 + wave * 64 < BCH) {  // wave-uniform
                const int D = j * 256 + wave * 64 + lane;
                const int G = D >> 3;
                const int s = (G << 3) | ((D & 7) ^ (G & 7));
                const int m = s >> 2, c4 = (s & 3) * 8;
                __builtin_amdgcn_global_load_lds(
                    (const AS1 unsigned*)(B + (size_t)(bn + m) * K + k0 + c4),
                    (AS3 unsigned*)&Bs[p][t][(j * 256 + wave * 64) * 8], 16, 0, 0);
            }
        }
    };

    const int nPair = K >> 6;   // K/64 double-rounds (768 -> 12)
    stage(0, 0, 0);
    stage(32, 0, 1);
    for (int it = 0; it < nPair; it++) {
        const int p = it & 1;
        __syncthreads();                       // drains both tiles of pair it
        if (it + 1 < nPair) {
            stage((2 * it + 2) << 5, p ^ 1, 0);
            stage((2 * it + 3) << 5, p ^ 1, 1);
        }
#pragma unroll
        for (int t = 0; t < 2; t++) {
            s16x8 af[4];
#pragma unroll
            for (int mt = 0; mt < 4; mt++) {
                const int m = wr * 64 + mt * 16 + l16;
                const int d = ((m & 1) * 4 + quad) ^ ((m >> 1) & 7);
                af[mt] = *(const s16x8*)&As[p][t][(m >> 1) * 64 + d * 8];
            }
#pragma unroll
            for (int nt = 0; nt < NTW; nt++) {
                const int n = wc * (TN / 2) + nt * 16 + l16;
                const int d = ((n & 1) * 4 + quad) ^ ((n >> 1) & 7);
                s16x8 bf = *(const s16x8*)&Bs[p][t][(n >> 1) * 64 + d * 8];
#pragma unroll
                for (int mt = 0; mt < 4; mt++)
                    acc[mt][nt] = __builtin_amdgcn_mfma_f32_16x16x32_bf16(
                        af[mt], bf, acc[mt][nt], 0, 0, 0);
            }
        }
    }

#pragma unroll
    for (int mt = 0; mt < 4; mt++)
#pragma unroll
        for (int r = 0; r < 4; r++) {
            const size_t row = bm + wr * 64 + mt * 16 + quad * 4 + r;
#pragma unroll
            for (int nt = 0; nt < NTW; nt++)
                Cout[row * N + bn + wc * (TN / 2) + nt * 16 + l16] = acc[mt][nt][r];
        }
}

// ---------------------------------------------------------------------------
// Flash attention v3 (S^T formulation) — R6 structure (proven 4-wave/256t):
//   - process_pair fuses both q-tiles on shared K/V fragment reads.
//   - P converted with v_perm_b32 packed truncation.
//   - P scratch aliases this wave's own store rows: qb in Ks[buf^1],
//     qa in Vs[buf^1].
// Complementary q-block pairing: 768 equal blocks = 3/CU.
// T5 setprio around MFMA clusters (R4 banked win).
// R9: raw v_exp_f32 (fexp2) on log2e-pre-folded scores — 1 transcendental
// per element, no libm wrapper (R8's exp2f was the slow precise path).
// ---------------------------------------------------------------------------
#define KSP 72
#define VSP 72

__global__ __launch_bounds__(256, 3) void flash_attn(const short* __restrict__ qkv,
                                                     short* __restrict__ y) {
    __shared__ short Ks[2][64 * KSP];
    __shared__ short Vs[2][64 * VSP];

    const int wave = threadIdx.x >> 6;
    const int lane = threadIdx.x & 63;
    const int l16  = lane & 15;
    const int quad = lane >> 4;

    const int pair = blockIdx.x / 96;     // 0..7
    const int bh   = blockIdx.x % 96;
    const int h = bh % Hh;
    const int b = bh / Hh;
    const int qa_blk = pair;
    const int qb_blk = 15 - pair;
    const int q0a = qa_blk * 64 + wave * 16;
    const int q0b = qb_blk * 64 + wave * 16;

    s16x8 qfa[2], qfb[2];
    {
        const short* qpa = qkv + (size_t)(b * Tt + q0a + l16) * QKV_N + h * Dd + quad * 8;
        const short* qpb = qkv + (size_t)(b * Tt + q0b + l16) * QKV_N + h * Dd + quad * 8;
        qfa[0] = *(const s16x8*)qpa;  qfa[1] = *(const s16x8*)(qpa + 32);
        qfb[0] = *(const s16x8*)qpb;  qfb[1] = *(const s16x8*)(qpb + 32);
    }

    f32x4 oa[4] = {}, ob[4] = {};
    float la = 0.f, lb = 0.f;

    const int krow = threadIdx.x >> 2;
    const int kd0  = (threadIdx.x & 3) * 16;
    const int key2 = (threadIdx.x & 31) * 2;
    const int dv0  = (threadIdx.x >> 5) * 8;

    s16x8 pk0, pk1, pv0, pv1;
    auto load_tile = [&](int kbase) {
        const short* kp = qkv + (size_t)(b * Tt + kbase + krow) * QKV_N + Cc + h * Dd + kd0;
        pk0 = *(const s16x8*)kp;
        pk1 = *(const s16x8*)(kp + 8);
        const short* vp = qkv + (size_t)(b * Tt + kbase + key2) * QKV_N + 2 * Cc + h * Dd + dv0;
        pv0 = *(const s16x8*)vp;
        pv1 = *(const s16x8*)(vp + QKV_N);
    };
    auto store_tile = [&](int buf) {
        *(s16x8*)&Ks[buf][krow * KSP + kd0]     = pk0;
        *(s16x8*)&Ks[buf][krow * KSP + kd0 + 8] = pk1;
#pragma unroll
        for (int j = 0; j < 8; j++) {
            ushort2 w; w.x = (unsigned short)pv0[j]; w.y = (unsigned short)pv1[j];
            *(ushort2*)&Vs[buf][(dv0 + j) * VSP + key2] = w;
        }
    };

    auto process_pair = [&](int buf, int kbase, bool mask_a) {
        short* pwb = &Ks[buf ^ 1][wave * 16 * KSP];
        short* pwa = &Vs[buf ^ 1][wave * 16 * VSP];
        f32x4 eb[4], ea[4];
        __builtin_amdgcn_s_setprio(1);          // T5: QK^T MFMA cluster
#pragma unroll
        for (int g = 0; g < 4; g++) {
            s16x8 kf0 = *(const s16x8*)&Ks[buf][(g * 16 + l16) * KSP + quad * 8];
            s16x8 kf1 = *(const s16x8*)&Ks[buf][(g * 16 + l16) * KSP + 32 + quad * 8];
            f32x4 zb = {}, za = {};
            zb = __builtin_amdgcn_mfma_f32_16x16x32_bf16(kf0, qfb[0], zb, 0, 0, 0);
            zb = __builtin_amdgcn_mfma_f32_16x16x32_bf16(kf1, qfb[1], zb, 0, 0, 0);
            za = __builtin_amdgcn_mfma_f32_16x16x32_bf16(kf0, qfa[0], za, 0, 0, 0);
            za = __builtin_amdgcn_mfma_f32_16x16x32_bf16(kf1, qfa[1], za, 0, 0, 0);
            eb[g] = zb; ea[g] = za;
        }
        __builtin_amdgcn_s_setprio(0);
        float rsb = 0.f, rsa = 0.f;
#pragma unroll
        for (int g = 0; g < 4; g++) {
#pragma unroll
            for (int r = 0; r < 4; r++) {
                float pb = fexp2(eb[g][r]); rsb += pb; eb[g][r] = pb;
                float pa = fexp2(ea[g][r]);
                if (mask_a) pa = (kbase + g * 16 + quad * 4 + r <= q0a + l16) ? pa : 0.0f;
                rsa += pa; ea[g][r] = pa;
            }
            uint2 ub, ua;
            ub.x = pkt(eb[g][1], eb[g][0]); ub.y = pkt(eb[g][3], eb[g][2]);
            ua.x = pkt(ea[g][1], ea[g][0]); ua.y = pkt(ea[g][3], ea[g][2]);
            *(uint2*)&pwb[l16 * KSP + g * 16 + quad * 4] = ub;
            *(uint2*)&pwa[l16 * VSP + g * 16 + quad * 4] = ua;
        }
        lb += rsb; la += rsa;
        __builtin_amdgcn_s_setprio(1);          // T5: PV MFMA cluster
#pragma unroll
        for (int c = 0; c < 2; c++) {
            s16x8 pbb = *(const s16x8*)&pwb[l16 * KSP + c * 32 + quad * 8];
            s16x8 pba = *(const s16x8*)&pwa[l16 * VSP + c * 32 + quad * 8];
#pragma unroll
            for (int nc = 0; nc < 4; nc++) {
                s16x8 vb = *(const s16x8*)&Vs[buf][(nc * 16 + l16) * VSP + c * 32 + quad * 8];
                ob[nc] = __builtin_amdgcn_mfma_f32_16x16x32_bf16(vb, pbb, ob[nc], 0, 0, 0);
                oa[nc] = __builtin_amdgcn_mfma_f32_16x16x32_bf16(vb, pba, oa[nc], 0, 0, 0);
            }
        }
        __builtin_amdgcn_s_setprio(0);
    };

    auto process_single = [&](int buf, int kbase, bool masked) {
        short* pw = &Ks[buf ^ 1][wave * 16 * KSP];
        f32x4 e[4];
        __builtin_amdgcn_s_setprio(1);          // T5: QK^T MFMA cluster
#pragma unroll
        for (int g = 0; g < 4; g++) {
            s16x8 kf0 = *(const s16x8*)&Ks[buf][(g * 16 + l16) * KSP + quad * 8];
            s16x8 kf1 = *(const s16x8*)&Ks[buf][(g * 16 + l16) * KSP + 32 + quad * 8];
            f32x4 z = {};
            z = __builtin_amdgcn_mfma_f32_16x16x32_bf16(kf0, qfb[0], z, 0, 0, 0);
            z = __builtin_amdgcn_mfma_f32_16x16x32_bf16(kf1, qfb[1], z, 0, 0, 0);
            e[g] = z;
        }
        __builtin_amdgcn_s_setprio(0);
        float rs = 0.f;
#pragma unroll
        for (int g = 0; g < 4; g++) {
#pragma unroll
            for (int r = 0; r < 4; r++) {
                float p = fexp2(e[g][r]);
                if (masked) p = (kbase + g * 16 + quad * 4 + r <= q0b + l16) ? p : 0.0f;
                rs += p; e[g][r] = p;
            }
            uint2 u;
            u.x = pkt(e[g][1], e[g][0]); u.y = pkt(e[g][3], e[g][2]);
            *(uint2*)&pw[l16 * KSP + g * 16 + quad * 4] = u;
        }
        lb += rs;
        __builtin_amdgcn_s_setprio(1);          // T5: PV MFMA cluster
#pragma unroll
        for (int c = 0; c < 2; c++) {
            s16x8 pb = *(const s16x8*)&pw[l16 * KSP + c * 32 + quad * 8];
#pragma unroll
            for (int nc = 0; nc < 4; nc++) {
                s16x8 vb = *(const s16x8*)&Vs[buf][(nc * 16 + l16) * VSP + c * 32 + quad * 8];
                ob[nc] = __builtin_amdgcn_mfma_f32_16x16x32_bf16(vb, pb, ob[nc], 0, 0, 0);
            }
        }
        __builtin_amdgcn_s_setprio(0);
    };

    load_tile(0);
    store_tile(0);
    for (int kt = 0; kt <= qb_blk; kt++) {
        __syncthreads();
        const int nb = (kt < qb_blk) ? (kt + 1) * 64 : qb_blk * 64;
        load_tile(nb);
        const int buf = kt & 1;
        const int kbase = kt * 64;
        if (kt <= qa_blk)
            process_pair(buf, kbase, kt == qa_blk);
        else
            process_single(buf, kbase, kt == qb_blk);
        store_tile(buf ^ 1);
    }

    float sa = la; sa += __shfl_xor(sa, 16, 64); sa += __shfl_xor(sa, 32, 64);
    float sb = lb; sb += __shfl_xor(sb, 16, 64); sb += __shfl_xor(sb, 32, 64);
    const float inva = 1.0f / sa;
    const float invb = 1.0f / sb;
    short* ypa = y + (size_t)(b * Tt + q0a + l16) * Cc + h * Dd + quad * 4;
    short* ypb = y + (size_t)(b * Tt + q0b + l16) * Cc + h * Dd + quad * 4;
#pragma unroll
    for (int nc = 0; nc < 4; nc++) {
        s16x4 va, vb2;
#pragma unroll
        for (int r = 0; r < 4; r++) {
            va[r]  = f2bf(oa[nc][r] * inva);
            vb2[r] = f2bf(ob[nc][r] * invb);
        }
        *(s16x4*)&ypa[nc * 16] = va;
        *(s16x4*)&ypb[nc * 16] = vb2;
    }
}

// ---------------------------------------------------------------------------
extern "C" void kernel_launch(void* const* d_in, const int* in_sizes, int n_in,
                              void* d_out, int out_size, void* d_ws, size_t ws_size,
                              hipStream_t stream) {
    const float* x      = (const float*)d_in[0];
    const float* w_qkv  = (const float*)d_in[1];
    const float* w_proj = (const float*)d_in[2];
    float* out = (float*)d_out;

    float2* cs    = (float2*)d_ws;                         // 1024*32 float2
    short* xb     = (short*)(cs + Tt * 32);                // 8192x768
    short* wqkvb  = xb + (size_t)M_ROWS * Cc;              // 2304x768 (sigma-permuted q/k rows)
    short* wprojb = wqkvb + (size_t)QKV_N * Cc;            // 768x768
    short* qkvb   = wprojb + (size_t)Cc * Cc;              // 8192x2304
    short* yb     = qkvb + (size_t)M_ROWS * QKV_N;         // 8192x768

    prep_kernel<<<PREP_THREADS / 256, 256, 0, stream>>>(
        x, w_qkv, w_proj, xb, wqkvb, wprojb, cs);

    // qkv = x @ w_qkv.T with fused RoPE + q-scale*log2e (bf16 out): 3/CU
    gemm_nt_mfma<1, 192><<<768, 256, 0, stream>>>(
        xb, wqkvb, qkvb, cs, M_ROWS, QKV_N, Cc, QKV_N / 192);

    flash_attn<<<96 * 8, 256, 0, stream>>>(qkvb, yb);

    // out = y @ w_proj.T (fp32 out): 512 blocks = 2/CU exact, double-pumped
    gemm_nt_proj2<96><<<512, 256, 0, stream>>>(
        yb, wprojb, out, M_ROWS, Cc, Cc, Cc / 96);
}